// Round 1
// baseline (913.498 us; speedup 1.0000x reference)
//
#include <hip/hip_runtime.h>
#include <hip/hip_bf16.h>
#include <math.h>

// 3-layer GCN on MI355X.
// Strategy: build destination-CSR per launch (ws is re-poisoned each call),
// then each layer = tiled LDS GEMM (64x64 W) + pull-aggregation (1 wave/node,
// lane=feature, register accumulate, fused bias+ELU). No fp32 atomics.

#define FDIM 64

// ---------- CSR build ----------

__global__ void zero_int_kernel(int* __restrict__ p, int n) {
    int i = blockIdx.x * blockDim.x + threadIdx.x;
    if (i < n) p[i] = 0;
}

__global__ void count_kernel(const int* __restrict__ col, int* __restrict__ cnt, int e) {
    int i = blockIdx.x * blockDim.x + threadIdx.x;
    if (i < e) atomicAdd(&cnt[col[i]], 1);
}

// dinv = rsqrt(cnt + 1)   (self loop makes deg >= 1 always)
__global__ void dinv_kernel(const int* __restrict__ cnt, float* __restrict__ dinv, int n) {
    int i = blockIdx.x * blockDim.x + threadIdx.x;
    if (i < n) dinv[i] = rsqrtf((float)cnt[i] + 1.0f);
}

// Single-block exclusive scan over cnt[0..n) -> rowptr[0..n]; also writes the
// exclusive value back into cnt[] to serve as the fill cursor.
__global__ void scan_kernel(int* __restrict__ cnt, int* __restrict__ rowptr, int n) {
    __shared__ int wsum[16];
    __shared__ int woff[16];
    __shared__ int carry_sh;
    const int t = threadIdx.x;          // 0..1023
    const int lane = t & 63;
    const int wid = t >> 6;
    if (t == 0) carry_sh = 0;
    __syncthreads();
    for (int base = 0; base < n; base += 1024) {
        int i = base + t;
        int v = (i < n) ? cnt[i] : 0;
        // inclusive scan within the 64-lane wave
        int x = v;
        #pragma unroll
        for (int off = 1; off < 64; off <<= 1) {
            int y = __shfl_up(x, off, 64);
            if (lane >= off) x += y;
        }
        if (lane == 63) wsum[wid] = x;
        __syncthreads();
        if (t == 0) {
            int s = carry_sh;
            #pragma unroll
            for (int w = 0; w < 16; w++) { int tmp = wsum[w]; woff[w] = s; s += tmp; }
            carry_sh = s;
        }
        __syncthreads();
        int excl = woff[wid] + (x - v);
        if (i < n) { rowptr[i] = excl; cnt[i] = excl; }
        __syncthreads();   // protect wsum/carry for next iteration
    }
    if (t == 0) rowptr[n] = carry_sh;
}

__global__ void fill_kernel(const int* __restrict__ row, const int* __restrict__ col,
                            int* __restrict__ cursor, int* __restrict__ adj, int e) {
    int i = blockIdx.x * blockDim.x + threadIdx.x;
    if (i < e) {
        int pos = atomicAdd(&cursor[col[i]], 1);
        adj[pos] = row[i];
    }
}

// ---------- per-layer compute ----------

// H[n,64] = X[n,64] @ W[64,64].  64-row tile per 256-thread block.
__global__ __launch_bounds__(256) void gemm_kernel(const float* __restrict__ X,
                                                   const float* __restrict__ W,
                                                   float* __restrict__ Hout, int n) {
    __shared__ float Ws[64][64];
    __shared__ float Xs[64][64];
    const int t = threadIdx.x;
    const int row0 = blockIdx.x * 64;
    #pragma unroll
    for (int i = t; i < 4096; i += 256) Ws[i >> 6][i & 63] = W[i];
    #pragma unroll
    for (int i = t; i < 4096; i += 256) {
        int r = i >> 6, c = i & 63;
        int gr = row0 + r;
        Xs[r][c] = (gr < n) ? X[(size_t)gr * FDIM + c] : 0.0f;
    }
    __syncthreads();
    const int j = t & 63;      // output column (lane)
    const int ng = t >> 6;     // row-group 0..3 (16 rows each)
    float acc[16];
    #pragma unroll
    for (int r = 0; r < 16; r++) acc[r] = 0.0f;
    for (int k = 0; k < 64; k++) {
        float w = Ws[k][j];                       // stride-1 across lanes: free
        #pragma unroll
        for (int r = 0; r < 16; r++)
            acc[r] += Xs[ng * 16 + r][k] * w;     // broadcast: free
    }
    #pragma unroll
    for (int r = 0; r < 16; r++) {
        int gr = row0 + ng * 16 + r;
        if (gr < n) Hout[(size_t)gr * FDIM + j] = acc[r];
    }
}

// out[v][f] = dinv[v] * ( dinv[v]*h[v][f] + sum_{u in N_in(v)} dinv[u]*h[u][f] ) + b[f]
// one wave per node, lane = feature; optional fused ELU.
__global__ __launch_bounds__(256) void agg_kernel(const float* __restrict__ h,
                                                  const int* __restrict__ adj,
                                                  const int* __restrict__ rowptr,
                                                  const float* __restrict__ dinv,
                                                  const float* __restrict__ bias,
                                                  float* __restrict__ out,
                                                  int n, int do_elu) {
    const int wave = blockIdx.x * 4 + (threadIdx.x >> 6);
    const int lane = threadIdx.x & 63;
    if (wave >= n) return;
    const int v = wave;
    const float dv = dinv[v];
    float acc = dv * h[(size_t)v * FDIM + lane];   // self loop (outer dv applied below)
    const int s = rowptr[v];
    const int e = rowptr[v + 1];
    for (int i = s; i < e; i++) {
        int u = adj[i];
        acc += dinv[u] * h[(size_t)u * FDIM + lane];
    }
    float r = acc * dv + bias[lane];
    if (do_elu) r = (r > 0.0f) ? r : (expf(r) - 1.0f);
    out[(size_t)v * FDIM + lane] = r;
}

// ---------- launch ----------

extern "C" void kernel_launch(void* const* d_in, const int* in_sizes, int n_in,
                              void* d_out, int out_size, void* d_ws, size_t ws_size,
                              hipStream_t stream) {
    const float* x   = (const float*)d_in[0];
    const int*   ei  = (const int*)d_in[1];
    const float* W1  = (const float*)d_in[2];
    const float* b1  = (const float*)d_in[3];
    const float* W2  = (const float*)d_in[4];
    const float* b2  = (const float*)d_in[5];
    const float* W3  = (const float*)d_in[6];
    const float* b3  = (const float*)d_in[7];

    const int N = in_sizes[0] / FDIM;      // 100000
    const int E = in_sizes[1] / 2;         // 1600000
    const int* erow = ei;                   // edge_index[0] : sources
    const int* ecol = ei + E;               // edge_index[1] : targets

    // workspace layout (bufA first for 16B alignment)
    char* p = (char*)d_ws;
    float* bufA   = (float*)p;  p += (size_t)N * FDIM * sizeof(float);   // 25.6 MB
    int*   cnt    = (int*)p;    p += (size_t)N * sizeof(int);            // histogram -> cursor
    float* dinv   = (float*)p;  p += (size_t)N * sizeof(float);
    int*   rowptr = (int*)p;    p += (size_t)(N + 1) * sizeof(int);
    int*   adj    = (int*)p;    p += (size_t)E * sizeof(int);

    float* outb = (float*)d_out;

    const int TB = 256;
    const int nblkN = (N + TB - 1) / TB;
    const int nblkE = (E + TB - 1) / TB;
    const int nblkG = (N + 63) / 64;        // gemm tiles
    const int nblkA = (N + 3) / 4;          // agg: 4 waves/block

    // CSR build (ws is poisoned every call, so rebuild each launch)
    zero_int_kernel<<<nblkN, TB, 0, stream>>>(cnt, N);
    count_kernel<<<nblkE, TB, 0, stream>>>(ecol, cnt, E);
    dinv_kernel<<<nblkN, TB, 0, stream>>>(cnt, dinv, N);
    scan_kernel<<<1, 1024, 0, stream>>>(cnt, rowptr, N);
    fill_kernel<<<nblkE, TB, 0, stream>>>(erow, ecol, cnt, adj, E);

    // layer 1: h1 = x@W1 -> bufA ; agg -> d_out (ELU)
    gemm_kernel<<<nblkG, TB, 0, stream>>>(x, W1, bufA, N);
    agg_kernel<<<nblkA, TB, 0, stream>>>(bufA, adj, rowptr, dinv, b1, outb, N, 1);
    // layer 2: h2 = out@W2 -> bufA ; agg -> d_out (ELU)
    gemm_kernel<<<nblkG, TB, 0, stream>>>(outb, W2, bufA, N);
    agg_kernel<<<nblkA, TB, 0, stream>>>(bufA, adj, rowptr, dinv, b2, outb, N, 1);
    // layer 3: h3 = out@W3 -> bufA ; agg -> d_out (no ELU)
    gemm_kernel<<<nblkG, TB, 0, stream>>>(outb, W3, bufA, N);
    agg_kernel<<<nblkA, TB, 0, stream>>>(bufA, adj, rowptr, dinv, b3, outb, N, 0);
}

// Round 2
// 608.958 us; speedup vs baseline: 1.5001x; 1.5001x over previous
//
#include <hip/hip_runtime.h>
#include <hip/hip_bf16.h>
#include <math.h>

// 3-layer GCN on MI355X.
// R1: parallel 3-phase scan (old single-block scan was ~1 CU serial);
//     GEMM epilogue pre-scales h by dinv[row] (removes per-edge dinv load);
//     agg edge-loop manually unrolled x4 for 4 outstanding gathers/wave (MLP).

#define FDIM 64

// ---------- CSR build ----------

__global__ void zero_int_kernel(int* __restrict__ p, int n) {
    int i = blockIdx.x * blockDim.x + threadIdx.x;
    if (i < n) p[i] = 0;
}

__global__ void count_kernel(const int* __restrict__ col, int* __restrict__ cnt, int e) {
    int i = blockIdx.x * blockDim.x + threadIdx.x;
    if (i < e) atomicAdd(&cnt[col[i]], 1);
}

// phase 1: per-1024-chunk sums
__global__ __launch_bounds__(256) void block_sum_kernel(const int* __restrict__ cnt,
                                                        int* __restrict__ psum, int n) {
    __shared__ int wred[4];
    const int t = threadIdx.x;
    const int base = blockIdx.x * 1024;
    int s = 0;
    #pragma unroll
    for (int j = 0; j < 4; j++) {
        int i = base + t + j * 256;
        s += (i < n) ? cnt[i] : 0;
    }
    #pragma unroll
    for (int off = 32; off > 0; off >>= 1) s += __shfl_down(s, off, 64);
    if ((t & 63) == 0) wred[t >> 6] = s;
    __syncthreads();
    if (t == 0) psum[blockIdx.x] = wred[0] + wred[1] + wred[2] + wred[3];
}

// phase 2: single block, exclusive scan of psum[0..nb); total -> *totalp
__global__ __launch_bounds__(1024) void scan_partials_kernel(int* __restrict__ psum,
                                                             int* __restrict__ totalp, int nb) {
    __shared__ int wsum[16];
    __shared__ int woff[16];
    __shared__ int carry_sh;
    const int t = threadIdx.x;
    const int lane = t & 63;
    const int wid = t >> 6;
    if (t == 0) carry_sh = 0;
    __syncthreads();
    for (int base = 0; base < nb; base += 1024) {
        int i = base + t;
        int v = (i < nb) ? psum[i] : 0;
        int x = v;
        #pragma unroll
        for (int off = 1; off < 64; off <<= 1) {
            int y = __shfl_up(x, off, 64);
            if (lane >= off) x += y;
        }
        if (lane == 63) wsum[wid] = x;
        __syncthreads();
        if (t == 0) {
            int s = carry_sh;
            #pragma unroll
            for (int w = 0; w < 16; w++) { int tmp = wsum[w]; woff[w] = s; s += tmp; }
            carry_sh = s;
        }
        __syncthreads();
        int excl = woff[wid] + (x - v);
        if (i < nb) psum[i] = excl;
        __syncthreads();
    }
    if (t == 0) *totalp = carry_sh;
}

// phase 3: local exclusive rescan + chunk offset; emits rowptr, cursor(=cnt), dinv
__global__ __launch_bounds__(1024) void scan_final_kernel(int* __restrict__ cnt,
                                                          const int* __restrict__ psum,
                                                          int* __restrict__ rowptr,
                                                          float* __restrict__ dinv, int n) {
    __shared__ int wsum[16];
    __shared__ int woff[16];
    const int t = threadIdx.x;
    const int lane = t & 63;
    const int wid = t >> 6;
    const int i = blockIdx.x * 1024 + t;
    int v = (i < n) ? cnt[i] : 0;
    int x = v;
    #pragma unroll
    for (int off = 1; off < 64; off <<= 1) {
        int y = __shfl_up(x, off, 64);
        if (lane >= off) x += y;
    }
    if (lane == 63) wsum[wid] = x;
    __syncthreads();
    if (t == 0) {
        int s = psum[blockIdx.x];
        #pragma unroll
        for (int w = 0; w < 16; w++) { int tmp = wsum[w]; woff[w] = s; s += tmp; }
    }
    __syncthreads();
    if (i < n) {
        int excl = woff[wid] + (x - v);
        rowptr[i] = excl;
        cnt[i] = excl;                       // fill cursor
        dinv[i] = rsqrtf((float)v + 1.0f);   // +1 self loop
    }
}

__global__ void fill_kernel(const int* __restrict__ row, const int* __restrict__ col,
                            int* __restrict__ cursor, int* __restrict__ adj, int e) {
    int i = blockIdx.x * blockDim.x + threadIdx.x;
    if (i < e) {
        int pos = atomicAdd(&cursor[col[i]], 1);
        adj[pos] = row[i];
    }
}

// ---------- per-layer compute ----------

// Hs[n,64] = dinv[row] * (X[n,64] @ W[64,64])   (pre-scaled for pull-agg)
__global__ __launch_bounds__(256) void gemm_kernel(const float* __restrict__ X,
                                                   const float* __restrict__ W,
                                                   const float* __restrict__ dinv,
                                                   float* __restrict__ Hout, int n) {
    __shared__ float Ws[64][64];
    __shared__ float Xs[64][64];
    const int t = threadIdx.x;
    const int row0 = blockIdx.x * 64;
    #pragma unroll
    for (int i = t; i < 4096; i += 256) Ws[i >> 6][i & 63] = W[i];
    #pragma unroll
    for (int i = t; i < 4096; i += 256) {
        int r = i >> 6, c = i & 63;
        int gr = row0 + r;
        Xs[r][c] = (gr < n) ? X[(size_t)gr * FDIM + c] : 0.0f;
    }
    __syncthreads();
    const int j = t & 63;
    const int ng = t >> 6;
    float acc[16];
    #pragma unroll
    for (int r = 0; r < 16; r++) acc[r] = 0.0f;
    for (int k = 0; k < 64; k++) {
        float w = Ws[k][j];
        #pragma unroll
        for (int r = 0; r < 16; r++)
            acc[r] += Xs[ng * 16 + r][k] * w;
    }
    #pragma unroll
    for (int r = 0; r < 16; r++) {
        int gr = row0 + ng * 16 + r;
        if (gr < n) Hout[(size_t)gr * FDIM + j] = acc[r] * dinv[gr];
    }
}

// out[v][f] = dinv[v] * ( hs[v][f] + sum_{u in N_in(v)} hs[u][f] ) + b[f]
// hs pre-scaled by dinv[u]. One wave/node, lane=feature. Unroll x4 for MLP.
__global__ __launch_bounds__(256) void agg_kernel(const float* __restrict__ hs,
                                                  const int* __restrict__ adj,
                                                  const int* __restrict__ rowptr,
                                                  const float* __restrict__ dinv,
                                                  const float* __restrict__ bias,
                                                  float* __restrict__ out,
                                                  int n, int do_elu) {
    const int v = blockIdx.x * 4 + (threadIdx.x >> 6);
    const int lane = threadIdx.x & 63;
    if (v >= n) return;
    const float dv = dinv[v];
    const int s = rowptr[v];
    const int e = rowptr[v + 1];
    float acc = hs[(size_t)v * FDIM + lane];   // self loop (pre-scaled)
    float a0 = 0.0f, a1 = 0.0f, a2 = 0.0f, a3 = 0.0f;
    int i = s;
    for (; i + 4 <= e; i += 4) {
        int u0 = adj[i];
        int u1 = adj[i + 1];
        int u2 = adj[i + 2];
        int u3 = adj[i + 3];
        float f0 = hs[(size_t)u0 * FDIM + lane];
        float f1 = hs[(size_t)u1 * FDIM + lane];
        float f2 = hs[(size_t)u2 * FDIM + lane];
        float f3 = hs[(size_t)u3 * FDIM + lane];
        a0 += f0; a1 += f1; a2 += f2; a3 += f3;
    }
    for (; i < e; i++) a0 += hs[(size_t)adj[i] * FDIM + lane];
    acc += (a0 + a1) + (a2 + a3);
    float r = acc * dv + bias[lane];
    if (do_elu) r = (r > 0.0f) ? r : (expf(r) - 1.0f);
    out[(size_t)v * FDIM + lane] = r;
}

// ---------- launch ----------

extern "C" void kernel_launch(void* const* d_in, const int* in_sizes, int n_in,
                              void* d_out, int out_size, void* d_ws, size_t ws_size,
                              hipStream_t stream) {
    const float* x   = (const float*)d_in[0];
    const int*   ei  = (const int*)d_in[1];
    const float* W1  = (const float*)d_in[2];
    const float* b1  = (const float*)d_in[3];
    const float* W2  = (const float*)d_in[4];
    const float* b2  = (const float*)d_in[5];
    const float* W3  = (const float*)d_in[6];
    const float* b3  = (const float*)d_in[7];

    const int N = in_sizes[0] / FDIM;      // 100000
    const int E = in_sizes[1] / 2;         // 1600000
    const int* erow = ei;                   // sources
    const int* ecol = ei + E;               // targets

    const int NB = (N + 1023) / 1024;       // scan chunks

    char* p = (char*)d_ws;
    float* bufA   = (float*)p;  p += (size_t)N * FDIM * sizeof(float);
    int*   cnt    = (int*)p;    p += (size_t)N * sizeof(int);
    float* dinv   = (float*)p;  p += (size_t)N * sizeof(float);
    int*   rowptr = (int*)p;    p += (size_t)(N + 1) * sizeof(int);
    int*   psum   = (int*)p;    p += (size_t)NB * sizeof(int);
    int*   adj    = (int*)p;    p += (size_t)E * sizeof(int);

    float* outb = (float*)d_out;

    const int TB = 256;
    const int nblkN = (N + TB - 1) / TB;
    const int nblkE = (E + TB - 1) / TB;
    const int nblkG = (N + 63) / 64;
    const int nblkA = (N + 3) / 4;

    zero_int_kernel<<<nblkN, TB, 0, stream>>>(cnt, N);
    count_kernel<<<nblkE, TB, 0, stream>>>(ecol, cnt, E);
    block_sum_kernel<<<NB, 256, 0, stream>>>(cnt, psum, N);
    scan_partials_kernel<<<1, 1024, 0, stream>>>(psum, rowptr + N, NB);
    scan_final_kernel<<<NB, 1024, 0, stream>>>(cnt, psum, rowptr, dinv, N);
    fill_kernel<<<nblkE, TB, 0, stream>>>(erow, ecol, cnt, adj, E);

    gemm_kernel<<<nblkG, TB, 0, stream>>>(x, W1, dinv, bufA, N);
    agg_kernel<<<nblkA, TB, 0, stream>>>(bufA, adj, rowptr, dinv, b1, outb, N, 1);
    gemm_kernel<<<nblkG, TB, 0, stream>>>(outb, W2, dinv, bufA, N);
    agg_kernel<<<nblkA, TB, 0, stream>>>(bufA, adj, rowptr, dinv, b2, outb, N, 1);
    gemm_kernel<<<nblkG, TB, 0, stream>>>(outb, W3, dinv, bufA, N);
    agg_kernel<<<nblkA, TB, 0, stream>>>(bufA, adj, rowptr, dinv, b3, outb, N, 0);
}

// Round 3
// 500.235 us; speedup vs baseline: 1.8261x; 1.2173x over previous
//
#include <hip/hip_runtime.h>
#include <hip/hip_bf16.h>
#include <math.h>

// 3-layer GCN on MI355X.
// R2: single atomic pass (rank = atomicAdd return in count phase; fill becomes
//     atomic-free scatter via rowptr[col]+rank). Agg: coalesced adj load of 64
//     edges/lane + __shfl broadcast (readlane), x8-unrolled independent gathers.

#define FDIM 64

// ---------- CSR build ----------

__global__ void zero_int_kernel(int* __restrict__ p, int n) {
    int i = blockIdx.x * blockDim.x + threadIdx.x;
    if (i < n) p[i] = 0;
}

// rank[i] = position of edge i within its destination bucket (atomic order)
__global__ void count_rank_kernel(const int* __restrict__ col, int* __restrict__ cnt,
                                  int* __restrict__ rank, int e) {
    int i = blockIdx.x * blockDim.x + threadIdx.x;
    if (i < e) rank[i] = atomicAdd(&cnt[col[i]], 1);
}

// phase 1: per-1024-chunk sums
__global__ __launch_bounds__(256) void block_sum_kernel(const int* __restrict__ cnt,
                                                        int* __restrict__ psum, int n) {
    __shared__ int wred[4];
    const int t = threadIdx.x;
    const int base = blockIdx.x * 1024;
    int s = 0;
    #pragma unroll
    for (int j = 0; j < 4; j++) {
        int i = base + t + j * 256;
        s += (i < n) ? cnt[i] : 0;
    }
    #pragma unroll
    for (int off = 32; off > 0; off >>= 1) s += __shfl_down(s, off, 64);
    if ((t & 63) == 0) wred[t >> 6] = s;
    __syncthreads();
    if (t == 0) psum[blockIdx.x] = wred[0] + wred[1] + wred[2] + wred[3];
}

// phase 2: single block, exclusive scan of psum[0..nb)
__global__ __launch_bounds__(1024) void scan_partials_kernel(int* __restrict__ psum,
                                                             int* __restrict__ totalp, int nb) {
    __shared__ int wsum[16];
    __shared__ int woff[16];
    __shared__ int carry_sh;
    const int t = threadIdx.x;
    const int lane = t & 63;
    const int wid = t >> 6;
    if (t == 0) carry_sh = 0;
    __syncthreads();
    for (int base = 0; base < nb; base += 1024) {
        int i = base + t;
        int v = (i < nb) ? psum[i] : 0;
        int x = v;
        #pragma unroll
        for (int off = 1; off < 64; off <<= 1) {
            int y = __shfl_up(x, off, 64);
            if (lane >= off) x += y;
        }
        if (lane == 63) wsum[wid] = x;
        __syncthreads();
        if (t == 0) {
            int s = carry_sh;
            #pragma unroll
            for (int w = 0; w < 16; w++) { int tmp = wsum[w]; woff[w] = s; s += tmp; }
            carry_sh = s;
        }
        __syncthreads();
        int excl = woff[wid] + (x - v);
        if (i < nb) psum[i] = excl;
        __syncthreads();
    }
    if (t == 0) *totalp = carry_sh;
}

// phase 3: local exclusive rescan + chunk offset; emits rowptr + dinv
__global__ __launch_bounds__(1024) void scan_final_kernel(const int* __restrict__ cnt,
                                                          const int* __restrict__ psum,
                                                          int* __restrict__ rowptr,
                                                          float* __restrict__ dinv, int n) {
    __shared__ int wsum[16];
    __shared__ int woff[16];
    const int t = threadIdx.x;
    const int lane = t & 63;
    const int wid = t >> 6;
    const int i = blockIdx.x * 1024 + t;
    int v = (i < n) ? cnt[i] : 0;
    int x = v;
    #pragma unroll
    for (int off = 1; off < 64; off <<= 1) {
        int y = __shfl_up(x, off, 64);
        if (lane >= off) x += y;
    }
    if (lane == 63) wsum[wid] = x;
    __syncthreads();
    if (t == 0) {
        int s = psum[blockIdx.x];
        #pragma unroll
        for (int w = 0; w < 16; w++) { int tmp = wsum[w]; woff[w] = s; s += tmp; }
    }
    __syncthreads();
    if (i < n) {
        int excl = woff[wid] + (x - v);
        rowptr[i] = excl;
        dinv[i] = rsqrtf((float)v + 1.0f);   // +1 self loop
    }
}

// atomic-free scatter: adj[rowptr[col]+rank] = row
__global__ void scatter_kernel(const int* __restrict__ row, const int* __restrict__ col,
                               const int* __restrict__ rank, const int* __restrict__ rowptr,
                               int* __restrict__ adj, int e) {
    int i = blockIdx.x * blockDim.x + threadIdx.x;
    if (i < e) {
        int c = col[i];
        adj[rowptr[c] + rank[i]] = row[i];
    }
}

// ---------- per-layer compute ----------

// Hs[n,64] = dinv[row] * (X[n,64] @ W[64,64])
__global__ __launch_bounds__(256) void gemm_kernel(const float* __restrict__ X,
                                                   const float* __restrict__ W,
                                                   const float* __restrict__ dinv,
                                                   float* __restrict__ Hout, int n) {
    __shared__ float Ws[64][64];
    __shared__ float Xs[64][64];
    const int t = threadIdx.x;
    const int row0 = blockIdx.x * 64;
    #pragma unroll
    for (int i = t; i < 4096; i += 256) Ws[i >> 6][i & 63] = W[i];
    #pragma unroll
    for (int i = t; i < 4096; i += 256) {
        int r = i >> 6, c = i & 63;
        int gr = row0 + r;
        Xs[r][c] = (gr < n) ? X[(size_t)gr * FDIM + c] : 0.0f;
    }
    __syncthreads();
    const int j = t & 63;
    const int ng = t >> 6;
    float acc[16];
    #pragma unroll
    for (int r = 0; r < 16; r++) acc[r] = 0.0f;
    for (int k = 0; k < 64; k++) {
        float w = Ws[k][j];
        #pragma unroll
        for (int r = 0; r < 16; r++)
            acc[r] += Xs[ng * 16 + r][k] * w;
    }
    #pragma unroll
    for (int r = 0; r < 16; r++) {
        int gr = row0 + ng * 16 + r;
        if (gr < n) Hout[(size_t)gr * FDIM + j] = acc[r] * dinv[gr];
    }
}

// out[v][f] = dinv[v] * ( hs[v][f] + sum_{u in N_in(v)} hs[u][f] ) + b[f]
// One wave/node, lane=feature. adj loaded 64-wide coalesced, broadcast via shfl.
__global__ __launch_bounds__(256) void agg_kernel(const float* __restrict__ hs,
                                                  const int* __restrict__ adj,
                                                  const int* __restrict__ rowptr,
                                                  const float* __restrict__ dinv,
                                                  const float* __restrict__ bias,
                                                  float* __restrict__ out,
                                                  int n, int do_elu) {
    const int v = blockIdx.x * 4 + (threadIdx.x >> 6);
    const int lane = threadIdx.x & 63;
    if (v >= n) return;
    const float dv = dinv[v];
    const int s = rowptr[v];
    const int e = rowptr[v + 1];
    float acc = hs[(size_t)v * FDIM + lane];   // self loop (pre-scaled)
    float a0 = 0.0f, a1 = 0.0f, a2 = 0.0f, a3 = 0.0f;
    float a4 = 0.0f, a5 = 0.0f, a6 = 0.0f, a7 = 0.0f;
    for (int base = s; base < e; base += 64) {
        const int m = e - base < 64 ? e - base : 64;    // edges this chunk
        int uvec = 0;
        if (lane < m) uvec = adj[base + lane];           // coalesced
        int j = 0;
        for (; j + 8 <= m; j += 8) {
            int u0 = __shfl(uvec, j + 0, 64);
            int u1 = __shfl(uvec, j + 1, 64);
            int u2 = __shfl(uvec, j + 2, 64);
            int u3 = __shfl(uvec, j + 3, 64);
            int u4 = __shfl(uvec, j + 4, 64);
            int u5 = __shfl(uvec, j + 5, 64);
            int u6 = __shfl(uvec, j + 6, 64);
            int u7 = __shfl(uvec, j + 7, 64);
            float f0 = hs[(size_t)u0 * FDIM + lane];
            float f1 = hs[(size_t)u1 * FDIM + lane];
            float f2 = hs[(size_t)u2 * FDIM + lane];
            float f3 = hs[(size_t)u3 * FDIM + lane];
            float f4 = hs[(size_t)u4 * FDIM + lane];
            float f5 = hs[(size_t)u5 * FDIM + lane];
            float f6 = hs[(size_t)u6 * FDIM + lane];
            float f7 = hs[(size_t)u7 * FDIM + lane];
            a0 += f0; a1 += f1; a2 += f2; a3 += f3;
            a4 += f4; a5 += f5; a6 += f6; a7 += f7;
        }
        for (; j < m; j++) {
            int u = __shfl(uvec, j, 64);
            a0 += hs[(size_t)u * FDIM + lane];
        }
    }
    acc += ((a0 + a1) + (a2 + a3)) + ((a4 + a5) + (a6 + a7));
    float r = acc * dv + bias[lane];
    if (do_elu) r = (r > 0.0f) ? r : (__expf(r) - 1.0f);
    out[(size_t)v * FDIM + lane] = r;
}

// ---------- launch ----------

extern "C" void kernel_launch(void* const* d_in, const int* in_sizes, int n_in,
                              void* d_out, int out_size, void* d_ws, size_t ws_size,
                              hipStream_t stream) {
    const float* x   = (const float*)d_in[0];
    const int*   ei  = (const int*)d_in[1];
    const float* W1  = (const float*)d_in[2];
    const float* b1  = (const float*)d_in[3];
    const float* W2  = (const float*)d_in[4];
    const float* b2  = (const float*)d_in[5];
    const float* W3  = (const float*)d_in[6];
    const float* b3  = (const float*)d_in[7];

    const int N = in_sizes[0] / FDIM;      // 100000
    const int E = in_sizes[1] / 2;         // 1600000
    const int* erow = ei;                   // sources
    const int* ecol = ei + E;               // targets

    const int NB = (N + 1023) / 1024;       // scan chunks

    char* p = (char*)d_ws;
    float* bufA   = (float*)p;  p += (size_t)N * FDIM * sizeof(float);
    int*   cnt    = (int*)p;    p += (size_t)N * sizeof(int);
    float* dinv   = (float*)p;  p += (size_t)N * sizeof(float);
    int*   rowptr = (int*)p;    p += (size_t)(N + 1) * sizeof(int);
    int*   psum   = (int*)p;    p += (size_t)NB * sizeof(int);
    int*   adj    = (int*)p;    p += (size_t)E * sizeof(int);
    int*   rank   = (int*)bufA;             // aliased: dead before first gemm

    float* outb = (float*)d_out;

    const int TB = 256;
    const int nblkN = (N + TB - 1) / TB;
    const int nblkE = (E + TB - 1) / TB;
    const int nblkG = (N + 63) / 64;
    const int nblkA = (N + 3) / 4;

    zero_int_kernel<<<nblkN, TB, 0, stream>>>(cnt, N);
    count_rank_kernel<<<nblkE, TB, 0, stream>>>(ecol, cnt, rank, E);
    block_sum_kernel<<<NB, 256, 0, stream>>>(cnt, psum, N);
    scan_partials_kernel<<<1, 1024, 0, stream>>>(psum, rowptr + N, NB);
    scan_final_kernel<<<NB, 1024, 0, stream>>>(cnt, psum, rowptr, dinv, N);
    scatter_kernel<<<nblkE, TB, 0, stream>>>(erow, ecol, rank, rowptr, adj, E);

    gemm_kernel<<<nblkG, TB, 0, stream>>>(x, W1, dinv, bufA, N);
    agg_kernel<<<nblkA, TB, 0, stream>>>(bufA, adj, rowptr, dinv, b1, outb, N, 1);
    gemm_kernel<<<nblkG, TB, 0, stream>>>(outb, W2, dinv, bufA, N);
    agg_kernel<<<nblkA, TB, 0, stream>>>(bufA, adj, rowptr, dinv, b2, outb, N, 1);
    gemm_kernel<<<nblkG, TB, 0, stream>>>(outb, W3, dinv, bufA, N);
    agg_kernel<<<nblkA, TB, 0, stream>>>(bufA, adj, rowptr, dinv, b3, outb, N, 0);
}

// Round 4
// 467.356 us; speedup vs baseline: 1.9546x; 1.0704x over previous
//
#include <hip/hip_runtime.h>
#include <hip/hip_bf16.h>
#include <math.h>

// 3-layer GCN on MI355X.
// R3: staged hs buffer in bf16 (halves agg gather + gemm store traffic;
//     accumulation stays fp32); cnt zeroing via hipMemsetAsync.
//     CSR build: single atomic pass (rank=atomicAdd return) + parallel scan +
//     atomic-free scatter. Agg: 1 wave/node, lane=feature, coalesced adj
//     chunk + shfl broadcast, x8 independent gathers.

#define FDIM 64

// ---------- CSR build ----------

// rank[i] = position of edge i within its destination bucket (atomic order)
__global__ void count_rank_kernel(const int* __restrict__ col, int* __restrict__ cnt,
                                  int* __restrict__ rank, int e) {
    int i = blockIdx.x * blockDim.x + threadIdx.x;
    if (i < e) rank[i] = atomicAdd(&cnt[col[i]], 1);
}

// phase 1: per-1024-chunk sums
__global__ __launch_bounds__(256) void block_sum_kernel(const int* __restrict__ cnt,
                                                        int* __restrict__ psum, int n) {
    __shared__ int wred[4];
    const int t = threadIdx.x;
    const int base = blockIdx.x * 1024;
    int s = 0;
    #pragma unroll
    for (int j = 0; j < 4; j++) {
        int i = base + t + j * 256;
        s += (i < n) ? cnt[i] : 0;
    }
    #pragma unroll
    for (int off = 32; off > 0; off >>= 1) s += __shfl_down(s, off, 64);
    if ((t & 63) == 0) wred[t >> 6] = s;
    __syncthreads();
    if (t == 0) psum[blockIdx.x] = wred[0] + wred[1] + wred[2] + wred[3];
}

// phase 2: single block, exclusive scan of psum[0..nb)
__global__ __launch_bounds__(1024) void scan_partials_kernel(int* __restrict__ psum,
                                                             int* __restrict__ totalp, int nb) {
    __shared__ int wsum[16];
    __shared__ int woff[16];
    __shared__ int carry_sh;
    const int t = threadIdx.x;
    const int lane = t & 63;
    const int wid = t >> 6;
    if (t == 0) carry_sh = 0;
    __syncthreads();
    for (int base = 0; base < nb; base += 1024) {
        int i = base + t;
        int v = (i < nb) ? psum[i] : 0;
        int x = v;
        #pragma unroll
        for (int off = 1; off < 64; off <<= 1) {
            int y = __shfl_up(x, off, 64);
            if (lane >= off) x += y;
        }
        if (lane == 63) wsum[wid] = x;
        __syncthreads();
        if (t == 0) {
            int s = carry_sh;
            #pragma unroll
            for (int w = 0; w < 16; w++) { int tmp = wsum[w]; woff[w] = s; s += tmp; }
            carry_sh = s;
        }
        __syncthreads();
        int excl = woff[wid] + (x - v);
        if (i < nb) psum[i] = excl;
        __syncthreads();
    }
    if (t == 0) *totalp = carry_sh;
}

// phase 3: local exclusive rescan + chunk offset; emits rowptr + dinv
__global__ __launch_bounds__(1024) void scan_final_kernel(const int* __restrict__ cnt,
                                                          const int* __restrict__ psum,
                                                          int* __restrict__ rowptr,
                                                          float* __restrict__ dinv, int n) {
    __shared__ int wsum[16];
    __shared__ int woff[16];
    const int t = threadIdx.x;
    const int lane = t & 63;
    const int wid = t >> 6;
    const int i = blockIdx.x * 1024 + t;
    int v = (i < n) ? cnt[i] : 0;
    int x = v;
    #pragma unroll
    for (int off = 1; off < 64; off <<= 1) {
        int y = __shfl_up(x, off, 64);
        if (lane >= off) x += y;
    }
    if (lane == 63) wsum[wid] = x;
    __syncthreads();
    if (t == 0) {
        int s = psum[blockIdx.x];
        #pragma unroll
        for (int w = 0; w < 16; w++) { int tmp = wsum[w]; woff[w] = s; s += tmp; }
    }
    __syncthreads();
    if (i < n) {
        int excl = woff[wid] + (x - v);
        rowptr[i] = excl;
        dinv[i] = rsqrtf((float)v + 1.0f);   // +1 self loop
    }
}

// atomic-free scatter: adj[rowptr[col]+rank] = row
__global__ void scatter_kernel(const int* __restrict__ row, const int* __restrict__ col,
                               const int* __restrict__ rank, const int* __restrict__ rowptr,
                               int* __restrict__ adj, int e) {
    int i = blockIdx.x * blockDim.x + threadIdx.x;
    if (i < e) {
        int c = col[i];
        adj[rowptr[c] + rank[i]] = row[i];
    }
}

// ---------- per-layer compute ----------

// Hs[n,64] = bf16( dinv[row] * (X[n,64] @ W[64,64]) )
__global__ __launch_bounds__(256) void gemm_kernel(const float* __restrict__ X,
                                                   const float* __restrict__ W,
                                                   const float* __restrict__ dinv,
                                                   __hip_bfloat16* __restrict__ Hout, int n) {
    __shared__ float Ws[64][64];
    __shared__ float Xs[64][64];
    const int t = threadIdx.x;
    const int row0 = blockIdx.x * 64;
    #pragma unroll
    for (int i = t; i < 4096; i += 256) Ws[i >> 6][i & 63] = W[i];
    #pragma unroll
    for (int i = t; i < 4096; i += 256) {
        int r = i >> 6, c = i & 63;
        int gr = row0 + r;
        Xs[r][c] = (gr < n) ? X[(size_t)gr * FDIM + c] : 0.0f;
    }
    __syncthreads();
    const int j = t & 63;
    const int ng = t >> 6;
    float acc[16];
    #pragma unroll
    for (int r = 0; r < 16; r++) acc[r] = 0.0f;
    for (int k = 0; k < 64; k++) {
        float w = Ws[k][j];
        #pragma unroll
        for (int r = 0; r < 16; r++)
            acc[r] += Xs[ng * 16 + r][k] * w;
    }
    #pragma unroll
    for (int r = 0; r < 16; r++) {
        int gr = row0 + ng * 16 + r;
        if (gr < n) Hout[(size_t)gr * FDIM + j] = __float2bfloat16(acc[r] * dinv[gr]);
    }
}

// out[v][f] = dinv[v] * ( hs[v][f] + sum_{u in N_in(v)} hs[u][f] ) + b[f]
// hs is bf16 pre-scaled by dinv[u]; accumulate fp32.
__global__ __launch_bounds__(256) void agg_kernel(const __hip_bfloat16* __restrict__ hs,
                                                  const int* __restrict__ adj,
                                                  const int* __restrict__ rowptr,
                                                  const float* __restrict__ dinv,
                                                  const float* __restrict__ bias,
                                                  float* __restrict__ out,
                                                  int n, int do_elu) {
    const int v = blockIdx.x * 4 + (threadIdx.x >> 6);
    const int lane = threadIdx.x & 63;
    if (v >= n) return;
    const float dv = dinv[v];
    const int s = rowptr[v];
    const int e = rowptr[v + 1];
    float acc = __bfloat162float(hs[(size_t)v * FDIM + lane]);   // self loop (pre-scaled)
    float a0 = 0.0f, a1 = 0.0f, a2 = 0.0f, a3 = 0.0f;
    float a4 = 0.0f, a5 = 0.0f, a6 = 0.0f, a7 = 0.0f;
    for (int base = s; base < e; base += 64) {
        const int m = e - base < 64 ? e - base : 64;
        int uvec = 0;
        if (lane < m) uvec = adj[base + lane];           // coalesced
        int j = 0;
        for (; j + 8 <= m; j += 8) {
            int u0 = __shfl(uvec, j + 0, 64);
            int u1 = __shfl(uvec, j + 1, 64);
            int u2 = __shfl(uvec, j + 2, 64);
            int u3 = __shfl(uvec, j + 3, 64);
            int u4 = __shfl(uvec, j + 4, 64);
            int u5 = __shfl(uvec, j + 5, 64);
            int u6 = __shfl(uvec, j + 6, 64);
            int u7 = __shfl(uvec, j + 7, 64);
            float f0 = __bfloat162float(hs[(size_t)u0 * FDIM + lane]);
            float f1 = __bfloat162float(hs[(size_t)u1 * FDIM + lane]);
            float f2 = __bfloat162float(hs[(size_t)u2 * FDIM + lane]);
            float f3 = __bfloat162float(hs[(size_t)u3 * FDIM + lane]);
            float f4 = __bfloat162float(hs[(size_t)u4 * FDIM + lane]);
            float f5 = __bfloat162float(hs[(size_t)u5 * FDIM + lane]);
            float f6 = __bfloat162float(hs[(size_t)u6 * FDIM + lane]);
            float f7 = __bfloat162float(hs[(size_t)u7 * FDIM + lane]);
            a0 += f0; a1 += f1; a2 += f2; a3 += f3;
            a4 += f4; a5 += f5; a6 += f6; a7 += f7;
        }
        for (; j < m; j++) {
            int u = __shfl(uvec, j, 64);
            a0 += __bfloat162float(hs[(size_t)u * FDIM + lane]);
        }
    }
    acc += ((a0 + a1) + (a2 + a3)) + ((a4 + a5) + (a6 + a7));
    float r = acc * dv + bias[lane];
    if (do_elu) r = (r > 0.0f) ? r : (__expf(r) - 1.0f);
    out[(size_t)v * FDIM + lane] = r;
}

// ---------- launch ----------

extern "C" void kernel_launch(void* const* d_in, const int* in_sizes, int n_in,
                              void* d_out, int out_size, void* d_ws, size_t ws_size,
                              hipStream_t stream) {
    const float* x   = (const float*)d_in[0];
    const int*   ei  = (const int*)d_in[1];
    const float* W1  = (const float*)d_in[2];
    const float* b1  = (const float*)d_in[3];
    const float* W2  = (const float*)d_in[4];
    const float* b2  = (const float*)d_in[5];
    const float* W3  = (const float*)d_in[6];
    const float* b3  = (const float*)d_in[7];

    const int N = in_sizes[0] / FDIM;      // 100000
    const int E = in_sizes[1] / 2;         // 1600000
    const int* erow = ei;                   // sources
    const int* ecol = ei + E;               // targets

    const int NB = (N + 1023) / 1024;       // scan chunks

    char* p = (char*)d_ws;
    __hip_bfloat16* hsb = (__hip_bfloat16*)p;  p += (size_t)N * FDIM * sizeof(__hip_bfloat16); // 12.8 MB
    int*   cnt    = (int*)p;    p += (size_t)N * sizeof(int);
    float* dinv   = (float*)p;  p += (size_t)N * sizeof(float);
    int*   rowptr = (int*)p;    p += (size_t)(N + 1) * sizeof(int);
    int*   psum   = (int*)p;    p += (size_t)NB * sizeof(int);
    int*   adj    = (int*)p;    p += (size_t)E * sizeof(int);
    int*   rank   = (int*)p;    p += (size_t)E * sizeof(int);   // dead after scatter

    float* outb = (float*)d_out;

    const int TB = 256;
    const int nblkE = (E + TB - 1) / TB;
    const int nblkG = (N + 63) / 64;
    const int nblkA = (N + 3) / 4;

    hipMemsetAsync(cnt, 0, (size_t)N * sizeof(int), stream);
    count_rank_kernel<<<nblkE, TB, 0, stream>>>(ecol, cnt, rank, E);
    block_sum_kernel<<<NB, 256, 0, stream>>>(cnt, psum, N);
    scan_partials_kernel<<<1, 1024, 0, stream>>>(psum, rowptr + N, NB);
    scan_final_kernel<<<NB, 1024, 0, stream>>>(cnt, psum, rowptr, dinv, N);
    scatter_kernel<<<nblkE, TB, 0, stream>>>(erow, ecol, rank, rowptr, adj, E);

    gemm_kernel<<<nblkG, TB, 0, stream>>>(x, W1, dinv, hsb, N);
    agg_kernel<<<nblkA, TB, 0, stream>>>(hsb, adj, rowptr, dinv, b1, outb, N, 1);
    gemm_kernel<<<nblkG, TB, 0, stream>>>(outb, W2, dinv, hsb, N);
    agg_kernel<<<nblkA, TB, 0, stream>>>(hsb, adj, rowptr, dinv, b2, outb, N, 1);
    gemm_kernel<<<nblkG, TB, 0, stream>>>(outb, W3, dinv, hsb, N);
    agg_kernel<<<nblkA, TB, 0, stream>>>(hsb, adj, rowptr, dinv, b3, outb, N, 0);
}

// Round 5
// 456.386 us; speedup vs baseline: 2.0016x; 1.0240x over previous
//
#include <hip/hip_runtime.h>
#include <hip/hip_bf16.h>
#include <math.h>

// 3-layer GCN on MI355X.
// R4: fixed-stride adjacency (adjF[col*C + rank], C chosen from ws_size;
//     wave-cooperative slow-path guard for deg>C) -> scan/rowptr eliminated.
//     Agg: lane = bfloat162 feature pair, half-waves process even/odd edges
//     (2 edges per gather instr, halved load+VALU per edge), fp32 accum.

#define FDIM 64

// ---------- CSR build ----------

// rank[i] = position of edge i within its destination bucket (atomic order)
__global__ void count_rank_kernel(const int* __restrict__ col, int* __restrict__ cnt,
                                  int* __restrict__ rank, int e) {
    int i = blockIdx.x * blockDim.x + threadIdx.x;
    if (i < e) rank[i] = atomicAdd(&cnt[col[i]], 1);
}

__global__ void dinv_kernel(const int* __restrict__ cnt, float* __restrict__ dinv, int n) {
    int i = blockIdx.x * blockDim.x + threadIdx.x;
    if (i < n) dinv[i] = rsqrtf((float)cnt[i] + 1.0f);   // +1 self loop
}

// adjF[col*cap + rank] = row  (atomic-free; rank>=cap edges handled by agg slow path)
__global__ void scatter_fixed_kernel(const int* __restrict__ row, const int* __restrict__ col,
                                     const int* __restrict__ rank, int* __restrict__ adjF,
                                     int e, int cap) {
    int i = blockIdx.x * blockDim.x + threadIdx.x;
    if (i < e) {
        int r = rank[i];
        if (r < cap) adjF[(size_t)col[i] * cap + r] = row[i];
    }
}

// ---------- per-layer compute ----------

// Hs[n,64] = bf16( dinv[row] * (X[n,64] @ W[64,64]) )
__global__ __launch_bounds__(256) void gemm_kernel(const float* __restrict__ X,
                                                   const float* __restrict__ W,
                                                   const float* __restrict__ dinv,
                                                   __hip_bfloat16* __restrict__ Hout, int n) {
    __shared__ float Ws[64][64];
    __shared__ float Xs[64][64];
    const int t = threadIdx.x;
    const int row0 = blockIdx.x * 64;
    #pragma unroll
    for (int i = t; i < 4096; i += 256) Ws[i >> 6][i & 63] = W[i];
    #pragma unroll
    for (int i = t; i < 4096; i += 256) {
        int r = i >> 6, c = i & 63;
        int gr = row0 + r;
        Xs[r][c] = (gr < n) ? X[(size_t)gr * FDIM + c] : 0.0f;
    }
    __syncthreads();
    const int j = t & 63;
    const int ng = t >> 6;
    float acc[16];
    #pragma unroll
    for (int r = 0; r < 16; r++) acc[r] = 0.0f;
    for (int k = 0; k < 64; k++) {
        float w = Ws[k][j];
        #pragma unroll
        for (int r = 0; r < 16; r++)
            acc[r] += Xs[ng * 16 + r][k] * w;
    }
    #pragma unroll
    for (int r = 0; r < 16; r++) {
        int gr = row0 + ng * 16 + r;
        if (gr < n) Hout[(size_t)gr * FDIM + j] = __float2bfloat16(acc[r] * dinv[gr]);
    }
}

// out[v][:] = dinv[v] * ( hs[v][:] + sum_{u in N_in(v)} hs[u][:] ) + b ; optional ELU.
// Wave per node. lane&31 = feature PAIR (bf16x2); lane>>5 = half (even/odd edges).
__global__ __launch_bounds__(256) void agg_kernel(const __hip_bfloat16* __restrict__ hs,
                                                  const int* __restrict__ adjF,
                                                  const int* __restrict__ cnt,
                                                  const float* __restrict__ dinv,
                                                  const float* __restrict__ bias,
                                                  float* __restrict__ out,
                                                  int n, int cap, int do_elu,
                                                  const int* __restrict__ erow,
                                                  const int* __restrict__ ecol, int etot) {
    const int v = blockIdx.x * 4 + (threadIdx.x >> 6);
    const int lane = threadIdx.x & 63;
    if (v >= n) return;
    const int f2 = lane & 31;
    const int half = lane >> 5;
    const float dv = dinv[v];
    const int deg = cnt[v];
    const __hip_bfloat162* __restrict__ hs2 = (const __hip_bfloat162*)hs;

    float2 a0 = {0.f,0.f}, a1 = {0.f,0.f}, a2 = {0.f,0.f}, a3 = {0.f,0.f};
    float2 a4 = {0.f,0.f}, a5 = {0.f,0.f}, a6 = {0.f,0.f}, a7 = {0.f,0.f};

    // self loop (add once: half 0 only)
    if (half == 0) {
        __hip_bfloat162 sv = hs2[(size_t)v * 32 + f2];
        a0.x = __bfloat162float(sv.x);
        a0.y = __bfloat162float(sv.y);
    }

    if (deg <= cap) {                       // fast path (always, in practice)
        const int* __restrict__ av = adjF + (size_t)v * cap;
        for (int base = 0; base < deg; base += 64) {
            int m = deg - base; if (m > 64) m = 64;
            int uvec = 0;
            if (lane < m) uvec = av[base + lane];        // coalesced
            const int pairs = m >> 1;
            int k = 0;
            for (; k + 8 <= pairs; k += 8) {
                int u0 = __shfl(uvec, 2*(k+0) + half, 64);
                int u1 = __shfl(uvec, 2*(k+1) + half, 64);
                int u2 = __shfl(uvec, 2*(k+2) + half, 64);
                int u3 = __shfl(uvec, 2*(k+3) + half, 64);
                int u4 = __shfl(uvec, 2*(k+4) + half, 64);
                int u5 = __shfl(uvec, 2*(k+5) + half, 64);
                int u6 = __shfl(uvec, 2*(k+6) + half, 64);
                int u7 = __shfl(uvec, 2*(k+7) + half, 64);
                __hip_bfloat162 b0 = hs2[(size_t)u0 * 32 + f2];
                __hip_bfloat162 b1 = hs2[(size_t)u1 * 32 + f2];
                __hip_bfloat162 b2 = hs2[(size_t)u2 * 32 + f2];
                __hip_bfloat162 b3 = hs2[(size_t)u3 * 32 + f2];
                __hip_bfloat162 b4 = hs2[(size_t)u4 * 32 + f2];
                __hip_bfloat162 b5 = hs2[(size_t)u5 * 32 + f2];
                __hip_bfloat162 b6 = hs2[(size_t)u6 * 32 + f2];
                __hip_bfloat162 b7 = hs2[(size_t)u7 * 32 + f2];
                a0.x += __bfloat162float(b0.x); a0.y += __bfloat162float(b0.y);
                a1.x += __bfloat162float(b1.x); a1.y += __bfloat162float(b1.y);
                a2.x += __bfloat162float(b2.x); a2.y += __bfloat162float(b2.y);
                a3.x += __bfloat162float(b3.x); a3.y += __bfloat162float(b3.y);
                a4.x += __bfloat162float(b4.x); a4.y += __bfloat162float(b4.y);
                a5.x += __bfloat162float(b5.x); a5.y += __bfloat162float(b5.y);
                a6.x += __bfloat162float(b6.x); a6.y += __bfloat162float(b6.y);
                a7.x += __bfloat162float(b7.x); a7.y += __bfloat162float(b7.y);
            }
            for (; k < pairs; k++) {
                int u = __shfl(uvec, 2*k + half, 64);
                __hip_bfloat162 b = hs2[(size_t)u * 32 + f2];
                a0.x += __bfloat162float(b.x); a0.y += __bfloat162float(b.y);
            }
            if (m & 1) {                                  // odd tail edge
                int u = __shfl(uvec, m - 1, 64);
                if (half == 0) {
                    __hip_bfloat162 b = hs2[(size_t)u * 32 + f2];
                    a1.x += __bfloat162float(b.x); a1.y += __bfloat162float(b.y);
                }
            }
        }
    } else {
        // slow path: deg > cap (prob ~0) — wave-cooperative scan of raw edges
        for (int base = 0; base < etot; base += 64) {
            int m = etot - base; if (m > 64) m = 64;
            int c = -1, r = 0;
            if (lane < m) { c = ecol[base + lane]; r = erow[base + lane]; }
            unsigned long long mask = __ballot(c == v);
            while (mask) {
                int j = __ffsll((long long)mask) - 1;
                mask &= mask - 1;
                int u = __shfl(r, j, 64);
                if (half == 0) {
                    __hip_bfloat162 b = hs2[(size_t)u * 32 + f2];
                    a0.x += __bfloat162float(b.x); a0.y += __bfloat162float(b.y);
                }
            }
        }
    }

    float2 tot;
    tot.x = ((a0.x + a1.x) + (a2.x + a3.x)) + ((a4.x + a5.x) + (a6.x + a7.x));
    tot.y = ((a0.y + a1.y) + (a2.y + a3.y)) + ((a4.y + a5.y) + (a6.y + a7.y));
    tot.x += __shfl_xor(tot.x, 32, 64);    // combine halves
    tot.y += __shfl_xor(tot.y, 32, 64);

    if (half == 0) {
        float2 bv = ((const float2*)bias)[f2];
        float rx = tot.x * dv + bv.x;
        float ry = tot.y * dv + bv.y;
        if (do_elu) {
            rx = (rx > 0.0f) ? rx : (__expf(rx) - 1.0f);
            ry = (ry > 0.0f) ? ry : (__expf(ry) - 1.0f);
        }
        ((float2*)out)[(size_t)v * 32 + f2] = make_float2(rx, ry);
    }
}

// ---------- launch ----------

extern "C" void kernel_launch(void* const* d_in, const int* in_sizes, int n_in,
                              void* d_out, int out_size, void* d_ws, size_t ws_size,
                              hipStream_t stream) {
    const float* x   = (const float*)d_in[0];
    const int*   ei  = (const int*)d_in[1];
    const float* W1  = (const float*)d_in[2];
    const float* b1  = (const float*)d_in[3];
    const float* W2  = (const float*)d_in[4];
    const float* b2  = (const float*)d_in[5];
    const float* W3  = (const float*)d_in[6];
    const float* b3  = (const float*)d_in[7];

    const int N = in_sizes[0] / FDIM;      // 100000
    const int E = in_sizes[1] / 2;         // 1600000
    const int* erow = ei;                   // sources
    const int* ecol = ei + E;               // targets

    char* p = (char*)d_ws;
    __hip_bfloat16* hsb = (__hip_bfloat16*)p;  p += (size_t)N * FDIM * sizeof(__hip_bfloat16); // 12.8 MB
    int*   cnt  = (int*)p;   p += (size_t)N * sizeof(int);
    float* dinv = (float*)p; p += (size_t)N * sizeof(float);
    int*   adjF = (int*)p;
    int*   rank = (int*)hsb;                // aliased: dead before gemm1 writes hs

    // adjacency capacity: biggest of {64,48,32} that fits the workspace
    size_t used = (size_t)(p - (char*)d_ws);
    int cap = 64;
    while (cap > 32 && used + (size_t)N * cap * sizeof(int) > ws_size) cap -= 16;

    float* outb = (float*)d_out;

    const int TB = 256;
    const int nblkN = (N + TB - 1) / TB;
    const int nblkE = (E + TB - 1) / TB;
    const int nblkG = (N + 63) / 64;
    const int nblkA = (N + 3) / 4;

    hipMemsetAsync(cnt, 0, (size_t)N * sizeof(int), stream);
    count_rank_kernel<<<nblkE, TB, 0, stream>>>(ecol, cnt, rank, E);
    dinv_kernel<<<nblkN, TB, 0, stream>>>(cnt, dinv, N);
    scatter_fixed_kernel<<<nblkE, TB, 0, stream>>>(erow, ecol, rank, adjF, E, cap);

    gemm_kernel<<<nblkG, TB, 0, stream>>>(x, W1, dinv, hsb, N);
    agg_kernel<<<nblkA, TB, 0, stream>>>(hsb, adjF, cnt, dinv, b1, outb, N, cap, 1, erow, ecol, E);
    gemm_kernel<<<nblkG, TB, 0, stream>>>(outb, W2, dinv, hsb, N);
    agg_kernel<<<nblkA, TB, 0, stream>>>(hsb, adjF, cnt, dinv, b2, outb, N, cap, 1, erow, ecol, E);
    gemm_kernel<<<nblkG, TB, 0, stream>>>(outb, W3, dinv, hsb, N);
    agg_kernel<<<nblkA, TB, 0, stream>>>(hsb, adjF, cnt, dinv, b3, outb, N, cap, 0, erow, ecol, E);
}